// Round 10
// baseline (202.744 us; speedup 1.0000x reference)
//
#include <hip/hip_runtime.h>
#include <hip/hip_bf16.h>

typedef unsigned short u16;
typedef unsigned int   u32;
typedef __attribute__((ext_vector_type(4))) float f32x4;
typedef __attribute__((ext_vector_type(8))) short bf16x8;
typedef __attribute__((ext_vector_type(4))) short bf16x4;

#define EMB   1024
#define SEQ   1024
#define HEADS 16
#define DH    64
#define BATCH 4
#define BH    64      // BATCH*HEADS
#define BS    4096    // BATCH*SEQ
#define LDP   72      // padded LDS row for legacy attn kernels
#define NEG_BIG (-1.0e30f)

__device__ __forceinline__ float b2f(u16 u){ return __uint_as_float(((u32)u) << 16); }
__device__ __forceinline__ u16 f2b(float f){
    u32 u = __float_as_uint(f);
    u32 r = u + 0x7fffu + ((u >> 16) & 1u);   // round-to-nearest-even
    return (u16)(r >> 16);
}
__device__ __forceinline__ void zero4(f32x4& v){ v[0]=0.f; v[1]=0.f; v[2]=0.f; v[3]=0.f; }
__device__ __forceinline__ ushort4 pk4(float a, float b, float c, float d){
    ushort4 p; p.x = f2b(a); p.y = f2b(b); p.z = f2b(c); p.w = f2b(d); return p;
}
// raw v_exp_f32: computes 2^x on gfx9xx
__device__ __forceinline__ float exp2g(float x){ return __builtin_amdgcn_exp2f(x); }

// async global->LDS, 16B per lane; LDS dest is wave-uniform base + lane*16
__device__ __forceinline__ void gld_lds16(const void* g, void* l){
    __builtin_amdgcn_global_load_lds(
        (const __attribute__((address_space(1))) u32*)g,
        (__attribute__((address_space(3))) u32*)l, 16, 0, 0);
}

// XOR-swizzled flat Nx64 bf16 tile: conflict-free b128 reads AND writes.
__device__ __forceinline__ u16* tptr(u16* base, int row, int col /*mult of 8*/){
    const int phys = ((col >> 3) ^ (row & 7));
    return base + row * 64 + (phys << 3);
}
__device__ __forceinline__ const u16* tptrc(const u16* base, int row, int col /*mult of 8*/){
    const int phys = ((col >> 3) ^ (row & 7));
    return base + row * 64 + (phys << 3);
}
// 8-byte granular read from the same swizzled layout (col multiple of 4)
__device__ __forceinline__ const u16* tptr8c(const u16* base, int row, int col /*mult of 4*/){
    const int chunk = ((col >> 3) ^ (row & 7));
    return base + row * 64 + (chunk << 3) + (col & 7);
}

// fp32 dual-column dot (scalar fallback path only)
__device__ __forceinline__ void dot2_f32(const float* __restrict__ x,
                                         const float* __restrict__ w, const int ws,
                                         float& a0, float& a1)
{
    float s0 = 0.f, s1 = 0.f;
    for (int e = 0; e < EMB; e += 4) {
        const float4 xv = *(const float4*)(x + e);
        const float2 w0 = *(const float2*)(w + (size_t)(e + 0) * ws);
        const float2 w1 = *(const float2*)(w + (size_t)(e + 1) * ws);
        const float2 w2 = *(const float2*)(w + (size_t)(e + 2) * ws);
        const float2 w3 = *(const float2*)(w + (size_t)(e + 3) * ws);
        s0 += xv.x * w0.x; s1 += xv.x * w0.y;
        s0 += xv.y * w1.x; s1 += xv.y * w1.y;
        s0 += xv.z * w2.x; s1 += xv.z * w2.y;
        s0 += xv.w * w3.x; s1 += xv.w * w3.y;
    }
    a0 = s0; a1 = s1;
}

// ===========================================================================
// TIER A kernels
// ===========================================================================

// W[h][e][d] -> WT[h*64+d][e] bf16 (which<3); Wo[e][j] -> WoT[j][e] (which==3).
// grid (256, 4) x 256.  (X conversion is fused into gemm128<0>.)
__global__ __launch_bounds__(256) void transpose_w(
    const float* __restrict__ Wk, const float* __restrict__ Wv, const float* __restrict__ Wq,
    const float* __restrict__ Wo, u16* __restrict__ WT, u16* __restrict__ WoT)
{
    __shared__ u16 T[64][LDP];
    const int which = blockIdx.y;
    const int bx = blockIdx.x, t = threadIdx.x;

    if (which < 3) {
        const float* __restrict__ W = (which == 0) ? Wk : (which == 1) ? Wv : Wq;
        const int h = bx >> 4, e0 = (bx & 15) * 64;
        #pragma unroll
        for (int i = 0; i < 16; ++i) {
            const int idx = i * 256 + t;
            const int e = idx >> 6, d = idx & 63;
            T[d][e] = f2b(W[(size_t)h * (EMB * DH) + (size_t)(e0 + e) * DH + d]);
        }
        __syncthreads();
        u16* dstb = WT + (size_t)which * (EMB * EMB / 16) * 16;   // which*1048576
        #pragma unroll
        for (int i = 0; i < 2; ++i) {
            const int idx = i * 256 + t;
            const int d = idx >> 3, e8 = (idx & 7) * 8;
            *(bf16x8*)(dstb + (size_t)(h * 64 + d) * EMB + e0 + e8) = *(const bf16x8*)&T[d][e8];
        }
    } else {
        const int j0 = (bx >> 4) * 64, e0 = (bx & 15) * 64;
        #pragma unroll
        for (int i = 0; i < 16; ++i) {
            const int idx = i * 256 + t;
            const int e = idx >> 6, d = idx & 63;
            T[d][e] = f2b(Wo[(size_t)(e0 + e) * EMB + j0 + d]);
        }
        __syncthreads();
        #pragma unroll
        for (int i = 0; i < 2; ++i) {
            const int idx = i * 256 + t;
            const int d = idx >> 3, e8 = (idx & 7) * 8;
            *(bf16x8*)(WoT + (size_t)(j0 + d) * EMB + e0 + e8) = *(const bf16x8*)&T[d][e8];
        }
    }
}

// Unified 128x128 bf16 GEMM, BK=64, XOR-swizzled tiles, 2x2 waves of 64x64.
// 48 KB LDS: B double-buffered via global_load_lds (counted vmcnt), A single-
// buffered with reg-prefetch issued before COMPUTE (R8 structure).
// MODE 0: QKV projection with FUSED X fp32->bf16 conversion: LOADA reads
//         2x float4 per chunk, WRITEA packs via v_cvt_pk_bf16_f32 (16 VALU
//         ops/thread/step, hidden under MFMA). Deletes the convert pass
//         (-48 MB HBM traffic net). vmcnt bookkeeping unchanged: at WRITEA(k)
//         only B(k+1)'s 4 gld_lds are newer than the A(k) regs.
//         Q pre-scaled by log2(e)/sqrt(SEQ) for exp2-domain attn softmax.
// MODE 1: out-projection (A=CTX bf16, B=WoT, +bias+ReLU -> fp32 OUT).
template<int MODE>
__global__ __launch_bounds__(256) void gemm128(
    const float* __restrict__ X0, const float* __restrict__ X1, const float* __restrict__ X2,
    const u16* __restrict__ Ab, const u16* __restrict__ WT,
    u16* __restrict__ Qw, u16* __restrict__ Kw, u16* __restrict__ Vt,
    const float* __restrict__ bo, float* __restrict__ OUT)
{
    __shared__ u16 As[128 * 64];      // 16 KB swizzled, single buffer
    __shared__ u16 Bs[2][128 * 64];   // 32 KB swizzled, double-buffered

    const int t = threadIdx.x;
    const int wave = t >> 6, lane = t & 63;
    const int quad = lane >> 4, l16 = lane & 15;
    const int wrow = wave >> 1, wcol = wave & 1;
    const int m0 = blockIdx.x * 128;
    const int n0 = blockIdx.y * 128;
    const int which = blockIdx.z;

    const float* __restrict__ Xa = (MODE == 0)
        ? ((which == 0) ? X0 : (which == 1) ? X1 : X2) : (const float*)nullptr;
    const u16* __restrict__ Bg = (MODE == 0) ? WT + (size_t)which * 1048576 : WT;

    f32x4 acc[4][4];
    #pragma unroll
    for (int mi = 0; mi < 4; ++mi)
        #pragma unroll
        for (int ni = 0; ni < 4; ++ni) zero4(acc[mi][ni]);

    float4 araw[8];   // MODE 0: fp32 A prefetch (32 VGPRs)
    bf16x8 abf[4];    // MODE 1: bf16 A prefetch (16 VGPRs)

    auto LOADA = [&](int kk){
        #pragma unroll
        for (int i = 0; i < 4; ++i) {
            const int c = i * 256 + t;
            const int row = c >> 3, col8 = (c & 7) * 8;
            if constexpr (MODE == 0) {
                const float* s = Xa + (size_t)(m0 + row) * EMB + kk + col8;
                araw[i * 2]     = *(const float4*)s;
                araw[i * 2 + 1] = *(const float4*)(s + 4);
            } else {
                abf[i] = *(const bf16x8*)(Ab + (size_t)(m0 + row) * EMB + kk + col8);
            }
        }
    };
    auto WRITEA = [&](){
        #pragma unroll
        for (int i = 0; i < 4; ++i) {
            const int c = i * 256 + t;
            const int row = c >> 3, col8 = (c & 7) * 8;
            if constexpr (MODE == 0) {
                union { bf16x8 v; u32 d[4]; } pk;
                const float4 a = araw[i * 2], b4 = araw[i * 2 + 1];
                asm("v_cvt_pk_bf16_f32 %0, %1, %2" : "=v"(pk.d[0]) : "v"(a.x),  "v"(a.y));
                asm("v_cvt_pk_bf16_f32 %0, %1, %2" : "=v"(pk.d[1]) : "v"(a.z),  "v"(a.w));
                asm("v_cvt_pk_bf16_f32 %0, %1, %2" : "=v"(pk.d[2]) : "v"(b4.x), "v"(b4.y));
                asm("v_cvt_pk_bf16_f32 %0, %1, %2" : "=v"(pk.d[3]) : "v"(b4.z), "v"(b4.w));
                *(bf16x8*)tptr(As, row, col8) = pk.v;
            } else {
                *(bf16x8*)tptr(As, row, col8) = abf[i];
            }
        }
    };
    auto STAGE_B = [&](int kk, int buf){
        #pragma unroll
        for (int j = 0; j < 4; ++j) {
            const int cg = wave * 4 + j;          // chunk-group (wave-uniform)
            const int c  = cg * 64 + lane;
            const int row = c >> 3;
            const int col = ((c ^ row) & 7) << 3;
            gld_lds16(Bg + (size_t)(n0 + row) * EMB + kk + col, &Bs[buf][cg * 512]);
        }
    };
    auto COMPUTE = [&](const u16* Bc){
        #pragma unroll
        for (int kb = 0; kb < 2; ++kb) {
            bf16x8 af[4], bf[4];
            #pragma unroll
            for (int mi = 0; mi < 4; ++mi)
                af[mi] = *(const bf16x8*)tptrc(As, wrow * 64 + mi * 16 + l16, kb * 32 + quad * 8);
            #pragma unroll
            for (int ni = 0; ni < 4; ++ni)
                bf[ni] = *(const bf16x8*)tptrc(Bc, wcol * 64 + ni * 16 + l16, kb * 32 + quad * 8);
            #pragma unroll
            for (int mi = 0; mi < 4; ++mi)
                #pragma unroll
                for (int ni = 0; ni < 4; ++ni)
                    acc[mi][ni] = __builtin_amdgcn_mfma_f32_16x16x32_bf16(af[mi], bf[ni], acc[mi][ni], 0, 0, 0);
        }
    };
    auto BAR = [&](){
        asm volatile("s_waitcnt lgkmcnt(0)" ::: "memory");
        __builtin_amdgcn_sched_barrier(0);
        __builtin_amdgcn_s_barrier();
        __builtin_amdgcn_sched_barrier(0);
    };

    // prologue: B(0) -> A(0)regs -> B(1); A(0) reg-wait leaves B(1) in flight
    STAGE_B(0, 0);
    LOADA(0);
    STAGE_B(64, 1);

    #pragma unroll
    for (int k = 0; k < 16; ++k) {
        WRITEA();              // compiler waits A(k) regs; B(k) (older) landed too
        BAR();                 // A(k) visible; all waves' B(k) complete
        if (k < 15) LOADA((k + 1) * 64);   // issue early: hidden under COMPUTE
        COMPUTE(&Bs[k & 1][0]);
        BAR();                 // readers of As and Bs[k&1] retired
        if (k < 14) STAGE_B((k + 2) * 64, k & 1);   // into the freed buffer
    }

    // epilogue: C row r = m0+wrow*64+mi*16+quad*4+reg; col j = n0+wcol*64+ni*16+l16
    #pragma unroll
    for (int mi = 0; mi < 4; ++mi) {
        const int r = m0 + wrow * 64 + mi * 16 + quad * 4;
        #pragma unroll
        for (int ni = 0; ni < 4; ++ni) {
            const int j = n0 + wcol * 64 + ni * 16 + l16;
            if (MODE == 1) {
                const float bias = bo[j];
                #pragma unroll
                for (int reg = 0; reg < 4; ++reg) {
                    float v = acc[mi][ni][reg] + bias;
                    if (v < 0.f) v = 0.f;
                    OUT[(size_t)(r + reg) * EMB + j] = v;
                }
            } else {
                const int h = j >> 6, d = j & 63;
                const int b = r >> 10, s = r & (SEQ - 1);
                const int bh = b * HEADS + h;
                if (which == 1) {           // V^T [bh][d][s], 4 consecutive s
                    *(ushort4*)(Vt + ((size_t)bh * DH + d) * SEQ + s) =
                        pk4(acc[mi][ni][0], acc[mi][ni][1], acc[mi][ni][2], acc[mi][ni][3]);
                } else {                    // K or Q: [bh][s][d]
                    // Q pre-scale: log2(e)/32 -> attn softmax in exp2 domain
                    u16* dst = (which == 0) ? Kw : Qw;
                    const float qsc = (which == 2) ? 0.03125f * 1.44269504088896f : 1.0f;
                    #pragma unroll
                    for (int reg = 0; reg < 4; ++reg)
                        dst[((size_t)bh * SEQ + s + reg) * DH + d] = f2b(acc[mi][ni][reg] * qsc);
                }
            }
        }
    }
}

// ===========================================================================
// attn_flash2 — Tier A attention, QBLK=128 (2 q-subtiles share K/V staging):
//   * swapped QK^T, exp2-domain softmax, cvt_pk P-pack, defer-max THR=11
//   * K/V double-buffered swizzled LDS, reg-prefetch, ONE barrier per tile
//   * qt pairing: co-resident blocks get qt and 7-qt -> constant per-CU work
// Expects Qg pre-scaled by log2(e)/32. grid (SEQ/128, BH).
// ===========================================================================
__global__ __launch_bounds__(256) void attn_flash2(
    const u16* __restrict__ Qg, const u16* __restrict__ Kg, const u16* __restrict__ Vg,
    u16* __restrict__ CTXb)
{
    __shared__ u16 Ks[2][64 * 64];   // 8 KB each, swizzled
    __shared__ u16 Vs[2][64 * 64];   // 8 KB each, swizzled (rows = d, cols = local s)

    const int t = threadIdx.x;
    const int wave = t >> 6, lane = t & 63;
    const int quad = lane >> 4, l16 = lane & 15;
    const int bh = blockIdx.y;
    const int qb = blockIdx.x & 7;
    const int qt = ((blockIdx.y >> 5) & 1) ? (7 - qb) : qb;   // balanced pairing
    const int b = bh >> 4, h = bh & (HEADS - 1);
    const int q0 = qt * 128;
    const int nt = 2 * qt + 2;       // k-tiles (64-wide) this block visits

    const u16* __restrict__ Kbase = Kg + (size_t)bh * SEQ * DH;
    const u16* __restrict__ Vbase = Vg + (size_t)bh * DH * SEQ;

    // Q fragments for both subtiles: q = q0 + st*64 + wave*16+l16, d = kb*32+quad*8
    bf16x8 qf[2][2];
    #pragma unroll
    for (int st = 0; st < 2; ++st) {
        const u16* qrow = Qg + ((size_t)bh * SEQ + q0 + st * 64 + wave * 16 + l16) * DH;
        qf[st][0] = *(const bf16x8*)(qrow + quad * 8);
        qf[st][1] = *(const bf16x8*)(qrow + 32 + quad * 8);
    }

    // prologue: stage tile 0 into buffer 0
    #pragma unroll
    for (int i = 0; i < 2; ++i) {
        const int c = i * 256 + t;
        const int row = c >> 3, col8 = (c & 7) * 8;
        const bf16x8 kv = *(const bf16x8*)(Kbase + (size_t)row * DH + col8);
        const bf16x8 vv = *(const bf16x8*)(Vbase + (size_t)row * SEQ + col8);
        *(bf16x8*)tptr(&Ks[0][0], row, col8) = kv;
        *(bf16x8*)tptr(&Vs[0][0], row, col8) = vv;
    }

    float m[2] = {NEG_BIG, NEG_BIG}, l[2] = {0.f, 0.f};
    f32x4 oacc[2][4];
    #pragma unroll
    for (int st = 0; st < 2; ++st)
        #pragma unroll
        for (int nd = 0; nd < 4; ++nd) zero4(oacc[st][nd]);

    __syncthreads();

    const int qin = wave * 16 + l16;   // lane's q row within its subtile
    int cur = 0;
    for (int c = 0; c < nt; ++c) {
        // issue prefetch of next K/V tile into regs (lands during compute)
        const int kn = ((c < nt - 1) ? c + 1 : c) * 64;
        bf16x8 kpre[2], vpre[2];
        #pragma unroll
        for (int i = 0; i < 2; ++i) {
            const int cc = i * 256 + t;
            const int row = cc >> 3, col8 = (cc & 7) * 8;
            kpre[i] = *(const bf16x8*)(Kbase + (size_t)(kn + row) * DH + col8);
            vpre[i] = *(const bf16x8*)(Vbase + (size_t)row * SEQ + kn + col8);
        }

        const u16* Kc = &Ks[cur][0];
        const u16* Vc = &Vs[cur][0];

        #pragma unroll
        for (int st = 0; st < 2; ++st) {
            const int lim = 2 * qt + st;      // last k-tile for this subtile
            if (c > lim) continue;            // wave-uniform (only st=0 at c=nt-1)
            const bool diag = (c == lim);

            // S^T = K·Q^T : sacc[ni] col = q (l16), row k = ni*16 + quad*4 + reg
            f32x4 sacc[4];
            #pragma unroll
            for (int ni = 0; ni < 4; ++ni) zero4(sacc[ni]);
            __builtin_amdgcn_s_setprio(1);
            #pragma unroll
            for (int kb = 0; kb < 2; ++kb) {
                #pragma unroll
                for (int ni = 0; ni < 4; ++ni) {
                    const bf16x8 kf = *(const bf16x8*)tptrc(Kc, ni * 16 + l16, kb * 32 + quad * 8);
                    sacc[ni] = __builtin_amdgcn_mfma_f32_16x16x32_bf16(kf, qf[st][kb], sacc[ni], 0, 0, 0);
                }
            }
            __builtin_amdgcn_s_setprio(0);

            // online softmax (exp2 domain)
            float tmx[4];
            #pragma unroll
            for (int ni = 0; ni < 4; ++ni) {
                #pragma unroll
                for (int reg = 0; reg < 4; ++reg) {
                    float s = sacc[ni][reg];
                    if (diag && (ni * 16 + quad * 4 + reg > qin)) s = NEG_BIG;
                    sacc[ni][reg] = s;
                }
                tmx[ni] = fmaxf(fmaxf(sacc[ni][0], sacc[ni][1]),
                                fmaxf(sacc[ni][2], sacc[ni][3]));
            }
            float pmax = fmaxf(fmaxf(tmx[0], tmx[1]), fmaxf(tmx[2], tmx[3]));
            pmax = fmaxf(pmax, __shfl_xor(pmax, 16));   // row-uniform across quads
            pmax = fmaxf(pmax, __shfl_xor(pmax, 32));

            // T13 defer-max: rescale only when some row's max grew by > 11 (log2)
            if (!__all((int)(pmax - m[st] <= 11.0f))) {
                const float mx = fmaxf(m[st], pmax);
                const float alpha = exp2g(m[st] - mx);
                m[st] = mx;
                l[st] *= alpha;
                #pragma unroll
                for (int reg = 0; reg < 4; ++reg) {
                    const float ar = __shfl(alpha, quad * 4 + reg);
                    #pragma unroll
                    for (int nd = 0; nd < 4; ++nd) oacc[st][nd][reg] *= ar;
                }
            }

            float rs = 0.f;
            bf16x4 pa[4];
            #pragma unroll
            for (int ni = 0; ni < 4; ++ni) {
                const float p0 = exp2g(sacc[ni][0] - m[st]);
                const float p1 = exp2g(sacc[ni][1] - m[st]);
                const float p2 = exp2g(sacc[ni][2] - m[st]);
                const float p3 = exp2g(sacc[ni][3] - m[st]);
                rs += (p0 + p1) + (p2 + p3);
                union { bf16x4 v; u32 d[2]; } pk;
                asm("v_cvt_pk_bf16_f32 %0, %1, %2" : "=v"(pk.d[0]) : "v"(p0), "v"(p1));
                asm("v_cvt_pk_bf16_f32 %0, %1, %2" : "=v"(pk.d[1]) : "v"(p2), "v"(p3));
                pa[ni] = pk.v;
            }
            rs += __shfl_xor(rs, 16);
            rs += __shfl_xor(rs, 32);
            l[st] += rs;

            // PV: oacc[st][nd](row q = quad*4+reg, col d = nd*16+l16) += P·V
            __builtin_amdgcn_s_setprio(1);
            #pragma unroll
            for (int ks = 0; ks < 4; ++ks) {
                #pragma unroll
                for (int nd = 0; nd < 4; ++nd) {
                    const bf16x4 vf = *(const bf16x4*)tptr8c(Vc, nd * 16 + l16, ks * 16 + quad * 4);
                    oacc[st][nd] = __builtin_amdgcn_mfma_f32_16x16x16bf16_1k(pa[ks], vf, oacc[st][nd], 0, 0, 0);
                }
            }
            __builtin_amdgcn_s_setprio(0);
        }

        // commit prefetched tile into the other buffer; single barrier per tile
        const int nxt = cur ^ 1;
        #pragma unroll
        for (int i = 0; i < 2; ++i) {
            const int cc = i * 256 + t;
            const int row = cc >> 3, col8 = (cc & 7) * 8;
            *(bf16x8*)tptr(&Ks[nxt][0], row, col8) = kpre[i];
            *(bf16x8*)tptr(&Vs[nxt][0], row, col8) = vpre[i];
        }
        __syncthreads();
        cur = nxt;
    }

    // epilogue: row q = q0 + st*64 + wave*16 + quad*4 + reg
    #pragma unroll
    for (int st = 0; st < 2; ++st) {
        #pragma unroll
        for (int reg = 0; reg < 4; ++reg) {
            const float il = 1.f / __shfl(l[st], quad * 4 + reg);
            const int q = q0 + st * 64 + wave * 16 + quad * 4 + reg;
            #pragma unroll
            for (int nd = 0; nd < 4; ++nd) {
                const int d = nd * 16 + l16;
                CTXb[(size_t)(b * SEQ + q) * EMB + h * DH + d] = f2b(oacc[st][nd][reg] * il);
            }
        }
    }
}

// ===========================================================================
// R9-proven kernels (fallback QKV + shared attention + out-proj)
// ===========================================================================

__global__ __launch_bounds__(256) void qkv_proj_mfma(
    const float* __restrict__ Xk, const float* __restrict__ Xv, const float* __restrict__ Xq,
    const float* __restrict__ Wk, const float* __restrict__ Wv, const float* __restrict__ Wq,
    u16* __restrict__ Kw, u16* __restrict__ Vw, u16* __restrict__ Qw)
{
    __shared__ u16 As[128][LDP];
    __shared__ u16 Bs[64][LDP];

    const int which = blockIdx.z;
    const float* __restrict__ X = (which == 0) ? Xk : (which == 1) ? Xv : Xq;
    const float* __restrict__ W = (which == 0) ? Wk : (which == 1) ? Wv : Wq;

    const int h    = blockIdx.y;
    const int m0   = blockIdx.x * 128;
    const int t    = threadIdx.x;
    const int wave = t >> 6, lane = t & 63;
    const int quad = lane >> 4, l16 = lane & 15;

    f32x4 acc[2][4];
    #pragma unroll
    for (int mi = 0; mi < 2; ++mi)
        #pragma unroll
        for (int ni = 0; ni < 4; ++ni) zero4(acc[mi][ni]);

    const size_t wbase = (size_t)h * EMB * DH;
    for (int k0 = 0; k0 < EMB; k0 += 64) {
        #pragma unroll
        for (int i = 0; i < 8; ++i) {
            const int idx = i * 256 + t;
            const int r = idx >> 4, c4 = (idx & 15) * 4;
            const float4 v = *(const float4*)(X + (size_t)(m0 + r) * EMB + k0 + c4);
            *(ushort4*)&As[r][c4] = pk4(v.x, v.y, v.z, v.w);
        }
        #pragma unroll
        for (int i = 0; i < 4; ++i) {
            const int d  = t & 63;
            const int e0 = (t >> 6) * 4 + i * 16;
            const float v0 = W[wbase + (size_t)(k0 + e0 + 0) * DH + d];
            const float v1 = W[wbase + (size_t)(k0 + e0 + 1) * DH + d];
            const float v2 = W[wbase + (size_t)(k0 + e0 + 2) * DH + d];
            const float v3 = W[wbase + (size_t)(k0 + e0 + 3) * DH + d];
            *(ushort4*)&Bs[d][e0] = pk4(v0, v1, v2, v3);
        }
        __syncthreads();

        #pragma unroll
        for (int kb = 0; kb < 2; ++kb) {
            bf16x8 bfr[4];
            #pragma unroll
            for (int ni = 0; ni < 4; ++ni)
                bfr[ni] = *(const bf16x8*)&Bs[ni * 16 + l16][kb * 32 + quad * 8];
            #pragma unroll
            for (int mi = 0; mi < 2; ++mi) {
                const bf16x8 af = *(const bf16x8*)&As[wave * 32 + mi * 16 + l16][kb * 32 + quad * 8];
                #pragma unroll
                for (int ni = 0; ni < 4; ++ni)
                    acc[mi][ni] = __builtin_amdgcn_mfma_f32_16x16x32_bf16(af, bfr[ni], acc[mi][ni], 0, 0, 0);
            }
        }
        __syncthreads();
    }

    const int b  = m0 >> 10;
    const int bh = b * HEADS + h;
    u16* __restrict__ RowDst = (which == 0) ? Kw : Qw;
    #pragma unroll
    for (int mi = 0; mi < 2; ++mi) {
        const int s_base = (m0 & (SEQ - 1)) + wave * 32 + mi * 16 + quad * 4;
        #pragma unroll
        for (int ni = 0; ni < 4; ++ni) {
            const int d = ni * 16 + l16;
            if (which != 1) {
                #pragma unroll
                for (int reg = 0; reg < 4; ++reg)
                    RowDst[((size_t)bh * SEQ + s_base + reg) * DH + d] = f2b(acc[mi][ni][reg]);
            } else {
                *(ushort4*)(Vw + ((size_t)bh * DH + d) * SEQ + s_base) =
                    pk4(acc[mi][ni][0], acc[mi][ni][1], acc[mi][ni][2], acc[mi][ni][3]);
            }
        }
    }
}

template<bool QWS, bool TOWS>
__global__ __launch_bounds__(256) void attn_flash(
    const float* __restrict__ Xq, const float* __restrict__ Wq,
    const u16* __restrict__ Qg, const u16* __restrict__ Kg, const u16* __restrict__ Vg,
    u16* __restrict__ CTXb, float* __restrict__ CTXf)
{
    __shared__ u16 Qs[64][LDP];
    union KVU {
        struct { u16 Ks[64][LDP]; u16 Vt[64][LDP]; } kv;
        struct { u16 Xs[64][LDP]; u16 WT[64][LDP]; } pr;
    };
    __shared__ KVU uu;
    __shared__ u16 Ps[64][LDP];

    const int t    = threadIdx.x;
    const int wave = t >> 6, lane = t & 63;
    const int quad = lane >> 4, l16 = lane & 15;
    const int qt = blockIdx.x, bh = blockIdx.y;
    const int b  = bh >> 4, h = bh & (HEADS - 1);
    const int q0 = qt * 64;

    if (QWS) {
        #pragma unroll
        for (int i = 0; i < 4; ++i) {
            const int idx = i * 256 + t;
            const int r = idx >> 4, c4 = (idx & 15) * 4;
            *(ushort4*)&Qs[r][c4] = *(const ushort4*)(Qg + ((size_t)bh * SEQ + q0 + r) * DH + c4);
        }
    } else {
        f32x4 qacc[4];
        #pragma unroll
        for (int ni = 0; ni < 4; ++ni) zero4(qacc[ni]);
        const size_t wbase = (size_t)h * EMB * DH;
        for (int k0 = 0; k0 < EMB; k0 += 64) {
            #pragma unroll
            for (int i = 0; i < 4; ++i) {
                const int idx = i * 256 + t;
                const int r = idx >> 4, c4 = (idx & 15) * 4;
                const float4 v = *(const float4*)(Xq + (size_t)(b * SEQ + q0 + r) * EMB + k0 + c4);
                *(ushort4*)&uu.pr.Xs[r][c4] = pk4(v.x, v.y, v.z, v.w);
            }
            #pragma unroll
            for (int i = 0; i < 4; ++i) {
                const int d  = t & 63;
                const int e0 = (t >> 6) * 4 + i * 16;
                const float v0 = Wq[wbase + (size_t)(k0 + e0 + 0) * DH + d];
                const float v1 = Wq[wbase + (size_t)(k0 + e0 + 1) * DH + d];
                const float v2 = Wq[wbase + (size_t)(k0 + e0 + 2) * DH + d];
                const float v3 = Wq[wbase + (size_t)(k0 + e0 + 3) * DH + d];
                *(ushort4*)&uu.pr.WT[d][e0] = pk4(v0, v1, v2, v3);
            }
            __syncthreads();
            #pragma unroll
            for (int kb = 0; kb < 2; ++kb) {
                const bf16x8 af = *(const bf16x8*)&uu.pr.Xs[wave * 16 + l16][kb * 32 + quad * 8];
                #pragma unroll
                for (int ni = 0; ni < 4; ++ni) {
                    const bf16x8 bf = *(const bf16x8*)&uu.pr.WT[ni * 16 + l16][kb * 32 + quad * 8];
                    qacc[ni] = __builtin_amdgcn_mfma_f32_16x16x32_bf16(af, bf, qacc[ni], 0, 0, 0);
                }
            }
            __syncthreads();
        }
        #pragma unroll
        for (int ni = 0; ni < 4; ++ni)
            #pragma unroll
            for (int reg = 0; reg < 4; ++reg)
                Qs[wave * 16 + quad * 4 + reg][ni * 16 + l16] = f2b(qacc[ni][reg]);
    }

    float m[4], l[4];
    #pragma unroll
    for (int reg = 0; reg < 4; ++reg) { m[reg] = NEG_BIG; l[reg] = 0.f; }
    f32x4 oacc[4];
    #pragma unroll
    for (int ni = 0; ni < 4; ++ni) zero4(oacc[ni]);
    __syncthreads();

    for (int c = 0; c <= qt; ++c) {
        const int k0 = c * 64;

        #pragma unroll
        for (int i = 0; i < 4; ++i) {
            const int idx = i * 256 + t;
            const int r = idx >> 4, c4 = (idx & 15) * 4;
            *(ushort4*)&uu.kv.Ks[r][c4] = *(const ushort4*)(Kg + ((size_t)bh * SEQ + k0 + r) * DH + c4);
        }
        #pragma unroll
        for (int i = 0; i < 4; ++i) {
            const int idx = i * 256 + t;
            const int r = idx >> 4, c4 = (idx & 15) * 4;
            *(ushort4*)&uu.kv.Vt[r][c4] = *(const ushort4*)(Vg + ((size_t)bh * DH + r) * SEQ + k0 + c4);
        }
        __syncthreads();

        f32x4 sacc[4];
        #pragma unroll
        for (int ni = 0; ni < 4; ++ni) zero4(sacc[ni]);
        #pragma unroll
        for (int kb = 0; kb < 2; ++kb) {
            const bf16x8 af = *(const bf16x8*)&Qs[wave * 16 + l16][kb * 32 + quad * 8];
            #pragma unroll
            for (int ni = 0; ni < 4; ++ni) {
                const bf16x8 bf = *(const bf16x8*)&uu.kv.Ks[ni * 16 + l16][kb * 32 + quad * 8];
                sacc[ni] = __builtin_amdgcn_mfma_f32_16x16x32_bf16(af, bf, sacc[ni], 0, 0, 0);
            }
        }

        const bool diag = (c == qt);
        #pragma unroll
        for (int reg = 0; reg < 4; ++reg) {
            const int rloc = quad * 4 + reg;
            float sv[4];
            #pragma unroll
            for (int ni = 0; ni < 4; ++ni) {
                float s = sacc[ni][reg] * 0.03125f;
                if (diag && (ni * 16 + l16 > wave * 16 + rloc)) s = NEG_BIG;
                sv[ni] = s;
            }
            float mx = fmaxf(fmaxf(sv[0], sv[1]), fmaxf(sv[2], sv[3]));
            mx = fmaxf(mx, m[reg]);
            #pragma unroll
            for (int off = 1; off < 16; off <<= 1) mx = fmaxf(mx, __shfl_xor(mx, off));
            const float alpha = __expf(m[reg] - mx);
            float rs = 0.f;
            #pragma unroll
            for (int ni = 0; ni < 4; ++ni) {
                const float p = __expf(sv[ni] - mx);
                Ps[wave * 16 + rloc][ni * 16 + l16] = f2b(p);
                rs += p;
            }
            #pragma unroll
            for (int off = 1; off < 16; off <<= 1) rs += __shfl_xor(rs, off);
            l[reg] = l[reg] * alpha + rs;
            m[reg] = mx;
            #pragma unroll
            for (int ni = 0; ni < 4; ++ni) oacc[ni][reg] *= alpha;
        }
        __syncthreads();

        #pragma unroll
        for (int kb = 0; kb < 2; ++kb) {
            const bf16x8 af = *(const bf16x8*)&Ps[wave * 16 + l16][kb * 32 + quad * 8];
            #pragma unroll
            for (int ni = 0; ni < 4; ++ni) {
                const bf16x8 bf = *(const bf16x8*)&uu.kv.Vt[ni * 16 + l16][kb * 32 + quad * 8];
                oacc[ni] = __builtin_amdgcn_mfma_f32_16x16x32_bf16(af, bf, oacc[ni], 0, 0, 0);
            }
        }
        __syncthreads();
    }

    float il[4];
    #pragma unroll
    for (int reg = 0; reg < 4; ++reg) il[reg] = 1.f / l[reg];
    #pragma unroll
    for (int ni = 0; ni < 4; ++ni) {
        const int d = ni * 16 + l16;
        #pragma unroll
        for (int reg = 0; reg < 4; ++reg) {
            const int q = wave * 16 + quad * 4 + reg;
            const float val = oacc[ni][reg] * il[reg];
            const size_t off = ((size_t)(b * SEQ + q0 + q)) * EMB + h * DH + d;
            if (TOWS) CTXb[off] = f2b(val);
            else      CTXf[off] = val;
        }
    }
}

__global__ __launch_bounds__(256) void out_proj_mfma(
    const u16* __restrict__ CTXb, const float* __restrict__ Wo,
    const float* __restrict__ bo, float* __restrict__ OUT)
{
    __shared__ u16 As[128][LDP];
    __shared__ u16 Bs[64][LDP];

    const int m0 = blockIdx.x * 128;
    const int n0 = blockIdx.y * 64;
    const int t = threadIdx.x;
    const int wave = t >> 6, lane = t & 63;
    const int quad = lane >> 4, l16 = lane & 15;

    f32x4 acc[2][4];
    #pragma unroll
    for (int mi = 0; mi < 2; ++mi)
        #pragma unroll
        for (int ni = 0; ni < 4; ++ni) zero4(acc[mi][ni]);

    for (int k0 = 0; k0 < EMB; k0 += 64) {
        #pragma unroll
        for (int i = 0; i < 8; ++i) {
            const int idx = i * 256 + t;
            const int r = idx >> 4, c4 = (idx & 15) * 4;
            *(ushort4*)&As[r][c4] = *(const ushort4*)(CTXb + (size_t)(m0 + r) * EMB + k0 + c4);
        }
        #pragma unroll
        for (int i = 0; i < 4; ++i) {
            const int d  = t & 63;
            const int e0 = (t >> 6) * 4 + i * 16;
            const float v0 = Wo[(size_t)(k0 + e0 + 0) * EMB + n0 + d];
            const float v1 = Wo[(size_t)(k0 + e0 + 1) * EMB + n0 + d];
            const float v2 = Wo[(size_t)(k0 + e0 + 2) * EMB + n0 + d];
            const float v3 = Wo[(size_t)(k0 + e0 + 3) * EMB + n0 + d];
            *(ushort4*)&Bs[d][e0] = pk4(v0, v1, v2, v3);
        }
        __syncthreads();
        #pragma unroll
        for (int kb = 0; kb < 2; ++kb) {
            bf16x8 bfr[4];
            #pragma unroll
            for (int ni = 0; ni < 4; ++ni)
                bfr[ni] = *(const bf16x8*)&Bs[ni * 16 + l16][kb * 32 + quad * 8];
            #pragma unroll
            for (int mi = 0; mi < 2; ++mi) {
                const bf16x8 af = *(const bf16x8*)&As[wave * 32 + mi * 16 + l16][kb * 32 + quad * 8];
                #pragma unroll
                for (int ni = 0; ni < 4; ++ni)
                    acc[mi][ni] = __builtin_amdgcn_mfma_f32_16x16x32_bf16(af, bfr[ni], acc[mi][ni], 0, 0, 0);
            }
        }
        __syncthreads();
    }

    #pragma unroll
    for (int mi = 0; mi < 2; ++mi) {
        const int row = m0 + wave * 32 + mi * 16 + quad * 4;
        #pragma unroll
        for (int ni = 0; ni < 4; ++ni) {
            const int col = n0 + ni * 16 + l16;
            const float bias = bo[col];
            #pragma unroll
            for (int reg = 0; reg < 4; ++reg) {
                float v = acc[mi][ni][reg] + bias;
                if (v < 0.f) v = 0.f;
                OUT[(size_t)(row + reg) * EMB + col] = v;
            }
        }
    }
}

__global__ __launch_bounds__(256) void out_proj_inplace(
    float* __restrict__ OUT, const float* __restrict__ Wo, const float* __restrict__ bo)
{
    __shared__ float Xs[8][EMB];
    const int t    = threadIdx.x;
    const int row0 = blockIdx.x * 8;
    {
        const float4* src = (const float4*)(OUT + (size_t)row0 * EMB);
        float4* dst = (float4*)&Xs[0][0];
        #pragma unroll
        for (int i = 0; i < 8; ++i) dst[i * 256 + t] = src[i * 256 + t];
    }
    __syncthreads();
    const int r  = t >> 5;
    const int j0 = (t & 31) * 2;
    const float* xrow = Xs[r];
    for (int jb = 0; jb < 16; ++jb) {
        const int j = jb * 64 + j0;
        float a0, a1;
        dot2_f32(xrow, Wo + j, EMB, a0, a1);
        a0 += bo[j];     if (a0 < 0.f) a0 = 0.f;
        a1 += bo[j + 1]; if (a1 < 0.f) a1 = 0.f;
        float* op = OUT + (size_t)(row0 + r) * EMB + j;
        op[0] = a0; op[1] = a1;
    }
}

// ---------------------------------------------------------------------------
extern "C" void kernel_launch(void* const* d_in, const int* in_sizes, int n_in,
                              void* d_out, int out_size, void* d_ws, size_t ws_size,
                              hipStream_t stream)
{
    const float* Xk = (const float*)d_in[0];
    const float* Xv = (const float*)d_in[1];
    const float* Xq = (const float*)d_in[2];
    const float* Wk = (const float*)d_in[3];
    const float* Wv = (const float*)d_in[4];
    const float* Wq = (const float*)d_in[5];
    const float* Wo = (const float*)d_in[6];
    const float* bo = (const float*)d_in[7];
    float* OUT = (float*)d_out;
    (void)in_sizes; (void)n_in; (void)out_size;

    const size_t SEGE = (size_t)BH * SEQ * DH;        // 4,194,304 elems
    const size_t SEGB = SEGE * sizeof(u16);           // 8 MB

    // Tier A ws layout (u16 elems):
    //   CTX (4M, former XB region) | WT (3*1M) | WoT (1M) | Qw | Kw | Vt
    const size_t XB_OFF  = 0;
    const size_t WT_OFF  = 3 * SEGE;                  // 12,582,912
    const size_t WOT_OFF = WT_OFF + 3 * (EMB * EMB / 64) * 64;  // +3*1,048,576
    const size_t QW_OFF  = WOT_OFF + (size_t)EMB * EMB;
    const size_t KW_OFF  = QW_OFF + SEGE;
    const size_t VT_OFF  = KW_OFF + SEGE;
    const size_t TIER_A_BYTES = (VT_OFF + SEGE) * sizeof(u16);  // 58,720,256

    if (ws_size >= TIER_A_BYTES) {
        u16* W16 = (u16*)d_ws;
        u16* WT  = W16 + WT_OFF;
        u16* WoT = W16 + WOT_OFF;
        u16* Qw  = W16 + QW_OFF;
        u16* Kw  = W16 + KW_OFF;
        u16* Vt  = W16 + VT_OFF;
        u16* CTX = W16 + XB_OFF;

        transpose_w<<<dim3(256, 4), 256, 0, stream>>>(Wk, Wv, Wq, Wo, WT, WoT);
        gemm128<0><<<dim3(32, 8, 3), 256, 0, stream>>>(
            Xk, Xv, Xq, nullptr, WT, Qw, Kw, Vt, nullptr, nullptr);
        attn_flash2<<<dim3(SEQ / 128, BH), 256, 0, stream>>>(Qw, Kw, Vt, CTX);
        gemm128<1><<<dim3(32, 8, 1), 256, 0, stream>>>(
            nullptr, nullptr, nullptr, CTX, WoT, nullptr, nullptr, nullptr, bo, OUT);
    } else if (ws_size >= 4 * SEGB) {
        u16* Qw = (u16*)d_ws;
        u16* Kw = Qw + SEGE;
        u16* Vw = Kw + SEGE;
        u16* CT = Vw + SEGE;
        qkv_proj_mfma<<<dim3(32, HEADS, 3), 256, 0, stream>>>(Xk, Xv, Xq, Wk, Wv, Wq, Kw, Vw, Qw);
        attn_flash<true, true><<<dim3(SEQ / 64, BH), 256, 0, stream>>>(
            Xq, Wq, Qw, Kw, Vw, CT, nullptr);
        out_proj_mfma<<<dim3(32, EMB / 64), 256, 0, stream>>>(CT, Wo, bo, OUT);
    } else if (ws_size >= 3 * SEGB) {
        u16* Kw = (u16*)d_ws;
        u16* Vw = Kw + SEGE;
        u16* CT = Vw + SEGE;
        qkv_proj_mfma<<<dim3(32, HEADS, 2), 256, 0, stream>>>(Xk, Xv, Xq, Wk, Wv, Wq, Kw, Vw, nullptr);
        attn_flash<false, true><<<dim3(SEQ / 64, BH), 256, 0, stream>>>(
            Xq, Wq, nullptr, Kw, Vw, CT, nullptr);
        out_proj_mfma<<<dim3(32, EMB / 64), 256, 0, stream>>>(CT, Wo, bo, OUT);
    } else {
        u16* Kw = (u16*)d_ws;
        u16* Vw = Kw + SEGE;
        qkv_proj_mfma<<<dim3(32, HEADS, 2), 256, 0, stream>>>(Xk, Xv, Xq, Wk, Wv, Wq, Kw, Vw, nullptr);
        attn_flash<false, false><<<dim3(SEQ / 64, BH), 256, 0, stream>>>(
            Xq, Wq, nullptr, Kw, Vw, nullptr, OUT);
        out_proj_inplace<<<dim3(BS / 8), 256, 0, stream>>>(OUT, Wo, bo);
    }
}

// Round 11
// 195.377 us; speedup vs baseline: 1.0377x; 1.0377x over previous
//
#include <hip/hip_runtime.h>
#include <hip/hip_bf16.h>

typedef unsigned short u16;
typedef unsigned int   u32;
typedef __attribute__((ext_vector_type(4))) float f32x4;
typedef __attribute__((ext_vector_type(8))) short bf16x8;
typedef __attribute__((ext_vector_type(4))) short bf16x4;

#define EMB   1024
#define SEQ   1024
#define HEADS 16
#define DH    64
#define BATCH 4
#define BH    64      // BATCH*HEADS
#define BS    4096    // BATCH*SEQ
#define LDP   72      // padded LDS row for legacy attn kernels
#define NEG_BIG (-1.0e30f)

__device__ __forceinline__ float b2f(u16 u){ return __uint_as_float(((u32)u) << 16); }
__device__ __forceinline__ u16 f2b(float f){
    u32 u = __float_as_uint(f);
    u32 r = u + 0x7fffu + ((u >> 16) & 1u);   // round-to-nearest-even
    return (u16)(r >> 16);
}
__device__ __forceinline__ void zero4(f32x4& v){ v[0]=0.f; v[1]=0.f; v[2]=0.f; v[3]=0.f; }
__device__ __forceinline__ ushort4 pk4(float a, float b, float c, float d){
    ushort4 p; p.x = f2b(a); p.y = f2b(b); p.z = f2b(c); p.w = f2b(d); return p;
}
// raw v_exp_f32: computes 2^x on gfx9xx
__device__ __forceinline__ float exp2g(float x){ return __builtin_amdgcn_exp2f(x); }

// async global->LDS, 16B per lane; LDS dest is wave-uniform base + lane*16
__device__ __forceinline__ void gld_lds16(const void* g, void* l){
    __builtin_amdgcn_global_load_lds(
        (const __attribute__((address_space(1))) u32*)g,
        (__attribute__((address_space(3))) u32*)l, 16, 0, 0);
}

// XOR-swizzled flat Nx64 bf16 tile: conflict-free b128 reads AND writes.
__device__ __forceinline__ u16* tptr(u16* base, int row, int col /*mult of 8*/){
    const int phys = ((col >> 3) ^ (row & 7));
    return base + row * 64 + (phys << 3);
}
__device__ __forceinline__ const u16* tptrc(const u16* base, int row, int col /*mult of 8*/){
    const int phys = ((col >> 3) ^ (row & 7));
    return base + row * 64 + (phys << 3);
}
// 8-byte granular read from the same swizzled layout (col multiple of 4)
__device__ __forceinline__ const u16* tptr8c(const u16* base, int row, int col /*mult of 4*/){
    const int chunk = ((col >> 3) ^ (row & 7));
    return base + row * 64 + (chunk << 3) + (col & 7);
}

// fp32 dual-column dot (scalar fallback path only)
__device__ __forceinline__ void dot2_f32(const float* __restrict__ x,
                                         const float* __restrict__ w, const int ws,
                                         float& a0, float& a1)
{
    float s0 = 0.f, s1 = 0.f;
    for (int e = 0; e < EMB; e += 4) {
        const float4 xv = *(const float4*)(x + e);
        const float2 w0 = *(const float2*)(w + (size_t)(e + 0) * ws);
        const float2 w1 = *(const float2*)(w + (size_t)(e + 1) * ws);
        const float2 w2 = *(const float2*)(w + (size_t)(e + 2) * ws);
        const float2 w3 = *(const float2*)(w + (size_t)(e + 3) * ws);
        s0 += xv.x * w0.x; s1 += xv.x * w0.y;
        s0 += xv.y * w1.x; s1 += xv.y * w1.y;
        s0 += xv.z * w2.x; s1 += xv.z * w2.y;
        s0 += xv.w * w3.x; s1 += xv.w * w3.y;
    }
    a0 = s0; a1 = s1;
}

// ===========================================================================
// TIER A kernels
// ===========================================================================

// X fp32 -> bf16, 3 tensors. grid (4096, 3) x 256.
// NOTE (R10 lesson): keep this as a standalone streaming pass — it runs at
// ~5.5 TB/s; fusing the fp32 read into gemm128<0> doubled the GEMM's
// A-traffic at its much lower effective BW and cost +23 us.
__global__ __launch_bounds__(256) void convert_x(
    const float* __restrict__ Xk, const float* __restrict__ Xv, const float* __restrict__ Xq,
    u16* __restrict__ XB)
{
    const int which = blockIdx.y;
    const float* __restrict__ src = (which == 0) ? Xk : (which == 1) ? Xv : Xq;
    const size_t off = (size_t)blockIdx.x * 1024 + threadIdx.x * 4;
    const float4 v = *(const float4*)(src + off);
    *(ushort4*)(XB + (size_t)which * 4194304 + off) = pk4(v.x, v.y, v.z, v.w);
}

// W[h][e][d] -> WT[h*64+d][e] bf16 (which<3); Wo[e][j] -> WoT[j][e] (which==3).
// grid (256, 4) x 256.
__global__ __launch_bounds__(256) void transpose_w(
    const float* __restrict__ Wk, const float* __restrict__ Wv, const float* __restrict__ Wq,
    const float* __restrict__ Wo, u16* __restrict__ WT, u16* __restrict__ WoT)
{
    __shared__ u16 T[64][LDP];
    const int which = blockIdx.y;
    const int bx = blockIdx.x, t = threadIdx.x;

    if (which < 3) {
        const float* __restrict__ W = (which == 0) ? Wk : (which == 1) ? Wv : Wq;
        const int h = bx >> 4, e0 = (bx & 15) * 64;
        #pragma unroll
        for (int i = 0; i < 16; ++i) {
            const int idx = i * 256 + t;
            const int e = idx >> 6, d = idx & 63;
            T[d][e] = f2b(W[(size_t)h * (EMB * DH) + (size_t)(e0 + e) * DH + d]);
        }
        __syncthreads();
        u16* dstb = WT + (size_t)which * (EMB * EMB / 16) * 16;   // which*1048576
        #pragma unroll
        for (int i = 0; i < 2; ++i) {
            const int idx = i * 256 + t;
            const int d = idx >> 3, e8 = (idx & 7) * 8;
            *(bf16x8*)(dstb + (size_t)(h * 64 + d) * EMB + e0 + e8) = *(const bf16x8*)&T[d][e8];
        }
    } else {
        const int j0 = (bx >> 4) * 64, e0 = (bx & 15) * 64;
        #pragma unroll
        for (int i = 0; i < 16; ++i) {
            const int idx = i * 256 + t;
            const int e = idx >> 6, d = idx & 63;
            T[d][e] = f2b(Wo[(size_t)(e0 + e) * EMB + j0 + d]);
        }
        __syncthreads();
        #pragma unroll
        for (int i = 0; i < 2; ++i) {
            const int idx = i * 256 + t;
            const int d = idx >> 3, e8 = (idx & 7) * 8;
            *(bf16x8*)(WoT + (size_t)(j0 + d) * EMB + e0 + e8) = *(const bf16x8*)&T[d][e8];
        }
    }
}

// Unified 128x128 bf16 GEMM, BK=64, XOR-swizzled tiles, 2x2 waves of 64x64.
// 48 KB LDS variant: B double-buffered via global_load_lds (counted vmcnt,
// never drain-0 in loop); A single-buffered with register prefetch issued
// BEFORE the compute phase (latency hidden under MFMA). 48 KB -> 3 blocks/CU.
// vmcnt bookkeeping: at WRITEA(k), only B(k+1)'s 4 loads are newer than the
// A(k) regs, so the compiler's reg-dependency wait is vmcnt(4) -- which also
// proves this wave's B(k) chunks (older) landed; barrier extends to all waves.
// MODE 0: QKV projection (blockIdx.z = which; epilogue scatters K/V^T/Q;
//         Q pre-scaled by log2(e)/sqrt(SEQ) for exp2-domain attn softmax).
// MODE 1: out-projection (A=CTX, B=WoT, +bias+ReLU -> fp32 OUT).
template<int MODE>
__global__ __launch_bounds__(256) void gemm128(
    const u16* __restrict__ XB, const u16* __restrict__ WT,
    u16* __restrict__ Qw, u16* __restrict__ Kw, u16* __restrict__ Vt,
    const float* __restrict__ bo, float* __restrict__ OUT)
{
    __shared__ u16 As[128 * 64];      // 16 KB swizzled, single buffer
    __shared__ u16 Bs[2][128 * 64];   // 32 KB swizzled, double-buffered

    const int t = threadIdx.x;
    const int wave = t >> 6, lane = t & 63;
    const int quad = lane >> 4, l16 = lane & 15;
    const int wrow = wave >> 1, wcol = wave & 1;
    const int m0 = blockIdx.x * 128;
    const int n0 = blockIdx.y * 128;
    const int which = blockIdx.z;

    const u16* __restrict__ Ag = (MODE == 0) ? XB + (size_t)which * 4194304 : XB;
    const u16* __restrict__ Bg = (MODE == 0) ? WT + (size_t)which * 1048576 : WT;

    f32x4 acc[4][4];
    #pragma unroll
    for (int mi = 0; mi < 4; ++mi)
        #pragma unroll
        for (int ni = 0; ni < 4; ++ni) zero4(acc[mi][ni]);

    bf16x8 areg[4];   // A-tile register prefetch buffer (16 VGPRs)

    auto LOADA = [&](int kk){
        #pragma unroll
        for (int i = 0; i < 4; ++i) {
            const int c = i * 256 + t;
            const int row = c >> 3, col8 = (c & 7) * 8;
            areg[i] = *(const bf16x8*)(Ag + (size_t)(m0 + row) * EMB + kk + col8);
        }
    };
    auto WRITEA = [&](){
        #pragma unroll
        for (int i = 0; i < 4; ++i) {
            const int c = i * 256 + t;
            const int row = c >> 3, col8 = (c & 7) * 8;
            *(bf16x8*)tptr(As, row, col8) = areg[i];
        }
    };
    auto STAGE_B = [&](int kk, int buf){
        #pragma unroll
        for (int j = 0; j < 4; ++j) {
            const int cg = wave * 4 + j;          // chunk-group (wave-uniform)
            const int c  = cg * 64 + lane;
            const int row = c >> 3;
            const int col = ((c ^ row) & 7) << 3;
            gld_lds16(Bg + (size_t)(n0 + row) * EMB + kk + col, &Bs[buf][cg * 512]);
        }
    };
    auto COMPUTE = [&](const u16* Bc){
        #pragma unroll
        for (int kb = 0; kb < 2; ++kb) {
            bf16x8 af[4], bf[4];
            #pragma unroll
            for (int mi = 0; mi < 4; ++mi)
                af[mi] = *(const bf16x8*)tptrc(As, wrow * 64 + mi * 16 + l16, kb * 32 + quad * 8);
            #pragma unroll
            for (int ni = 0; ni < 4; ++ni)
                bf[ni] = *(const bf16x8*)tptrc(Bc, wcol * 64 + ni * 16 + l16, kb * 32 + quad * 8);
            #pragma unroll
            for (int mi = 0; mi < 4; ++mi)
                #pragma unroll
                for (int ni = 0; ni < 4; ++ni)
                    acc[mi][ni] = __builtin_amdgcn_mfma_f32_16x16x32_bf16(af[mi], bf[ni], acc[mi][ni], 0, 0, 0);
        }
    };
    auto BAR = [&](){
        asm volatile("s_waitcnt lgkmcnt(0)" ::: "memory");
        __builtin_amdgcn_sched_barrier(0);
        __builtin_amdgcn_s_barrier();
        __builtin_amdgcn_sched_barrier(0);
    };

    // prologue: B(0) -> A(0)regs -> B(1); A(0) reg-wait = vmcnt(4) (B(1) flight)
    STAGE_B(0, 0);
    LOADA(0);
    STAGE_B(64, 1);

    #pragma unroll
    for (int k = 0; k < 16; ++k) {
        WRITEA();              // compiler waits A(k) regs -> vmcnt(4): B(k) landed too
        BAR();                 // A(k) visible; all waves' B(k) complete
        if (k < 15) LOADA((k + 1) * 64);   // issue early: hidden under COMPUTE
        COMPUTE(&Bs[k & 1][0]);
        BAR();                 // readers of As and Bs[k&1] retired
        if (k < 14) STAGE_B((k + 2) * 64, k & 1);   // into the freed buffer
    }

    // epilogue: C row r = m0+wrow*64+mi*16+quad*4+reg; col j = n0+wcol*64+ni*16+l16
    #pragma unroll
    for (int mi = 0; mi < 4; ++mi) {
        const int r = m0 + wrow * 64 + mi * 16 + quad * 4;
        #pragma unroll
        for (int ni = 0; ni < 4; ++ni) {
            const int j = n0 + wcol * 64 + ni * 16 + l16;
            if (MODE == 1) {
                const float bias = bo[j];
                #pragma unroll
                for (int reg = 0; reg < 4; ++reg) {
                    float v = acc[mi][ni][reg] + bias;
                    if (v < 0.f) v = 0.f;
                    OUT[(size_t)(r + reg) * EMB + j] = v;
                }
            } else {
                const int h = j >> 6, d = j & 63;
                const int b = r >> 10, s = r & (SEQ - 1);
                const int bh = b * HEADS + h;
                if (which == 1) {           // V^T [bh][d][s], 4 consecutive s
                    *(ushort4*)(Vt + ((size_t)bh * DH + d) * SEQ + s) =
                        pk4(acc[mi][ni][0], acc[mi][ni][1], acc[mi][ni][2], acc[mi][ni][3]);
                } else {                    // K or Q: [bh][s][d]
                    // Q pre-scale: log2(e)/32 -> attn softmax in exp2 domain
                    u16* dst = (which == 0) ? Kw : Qw;
                    const float qsc = (which == 2) ? 0.03125f * 1.44269504088896f : 1.0f;
                    #pragma unroll
                    for (int reg = 0; reg < 4; ++reg)
                        dst[((size_t)bh * SEQ + s + reg) * DH + d] = f2b(acc[mi][ni][reg] * qsc);
                }
            }
        }
    }
}

// ===========================================================================
// attn_flash2 — Tier A attention:
//   * swapped QK^T (S^T = K·Q^T): each lane owns one full q-row of scores
//   * softmax in exp2 domain (log2e folded into Q pre-scale): raw v_exp_f32
//   * P packed to bf16 via v_cvt_pk_bf16_f32 (2 ops per 4 values vs 20)
//   * defer-max (T13, THR=11 in log2 ~ HK's 8 in ln): skip O-rescale when
//     no row's max grew; row-reduced pmax BEFORE the vote (masked-lane safe)
//   * K/V double-buffered in XOR-swizzled LDS, reg-prefetch before MFMA,
//     committed after PV: ONE barrier per tile
//   * qt remapped so co-resident blocks get staggered causal depth
// Expects Qg pre-scaled by log2(e)/32.
// ===========================================================================
__global__ __launch_bounds__(256) void attn_flash2(
    const u16* __restrict__ Qg, const u16* __restrict__ Kg, const u16* __restrict__ Vg,
    u16* __restrict__ CTXb)
{
    __shared__ u16 Ks[2][64 * 64];   // 8 KB each, swizzled
    __shared__ u16 Vs[2][64 * 64];   // 8 KB each, swizzled (rows = d, cols = local s)

    const int t = threadIdx.x;
    const int wave = t >> 6, lane = t & 63;
    const int quad = lane >> 4, l16 = lane & 15;
    const int bh = blockIdx.y;
    const int qt = (blockIdx.x + (blockIdx.y >> 2)) & 15;
    const int b = bh >> 4, h = bh & (HEADS - 1);
    const int q0 = qt * 64;

    const u16* __restrict__ Kbase = Kg + (size_t)bh * SEQ * DH;
    const u16* __restrict__ Vbase = Vg + (size_t)bh * DH * SEQ;

    // Q fragment (B operand): q = wave*16+l16, d = kb*32+quad*8
    bf16x8 qf[2];
    {
        const u16* qrow = Qg + ((size_t)bh * SEQ + q0 + wave * 16 + l16) * DH;
        qf[0] = *(const bf16x8*)(qrow + quad * 8);
        qf[1] = *(const bf16x8*)(qrow + 32 + quad * 8);
    }

    // prologue: stage tile 0 into buffer 0
    #pragma unroll
    for (int i = 0; i < 2; ++i) {
        const int c = i * 256 + t;
        const int row = c >> 3, col8 = (c & 7) * 8;
        const bf16x8 kv = *(const bf16x8*)(Kbase + (size_t)row * DH + col8);
        const bf16x8 vv = *(const bf16x8*)(Vbase + (size_t)row * SEQ + col8);
        *(bf16x8*)tptr(&Ks[0][0], row, col8) = kv;
        *(bf16x8*)tptr(&Vs[0][0], row, col8) = vv;
    }

    float m = NEG_BIG, l = 0.f;
    f32x4 oacc[4];
    #pragma unroll
    for (int nd = 0; nd < 4; ++nd) zero4(oacc[nd]);

    __syncthreads();

    const int qin = wave * 16 + l16;   // this lane's q row (tile-local)
    int cur = 0;
    for (int c = 0; c <= qt; ++c) {
        // issue prefetch of next K/V tile into regs (lands during compute)
        const int kn = ((c < qt) ? c + 1 : qt) * 64;
        bf16x8 kpre[2], vpre[2];
        #pragma unroll
        for (int i = 0; i < 2; ++i) {
            const int cc = i * 256 + t;
            const int row = cc >> 3, col8 = (cc & 7) * 8;
            kpre[i] = *(const bf16x8*)(Kbase + (size_t)(kn + row) * DH + col8);
            vpre[i] = *(const bf16x8*)(Vbase + (size_t)row * SEQ + kn + col8);
        }

        const u16* Kc = &Ks[cur][0];
        const u16* Vc = &Vs[cur][0];

        // S^T = K·Q^T : sacc[ni] col = q (l16), row k = ni*16 + quad*4 + reg
        f32x4 sacc[4];
        #pragma unroll
        for (int ni = 0; ni < 4; ++ni) zero4(sacc[ni]);
        __builtin_amdgcn_s_setprio(1);
        #pragma unroll
        for (int kb = 0; kb < 2; ++kb) {
            #pragma unroll
            for (int ni = 0; ni < 4; ++ni) {
                const bf16x8 kf = *(const bf16x8*)tptrc(Kc, ni * 16 + l16, kb * 32 + quad * 8);
                sacc[ni] = __builtin_amdgcn_mfma_f32_16x16x32_bf16(kf, qf[kb], sacc[ni], 0, 0, 0);
            }
        }
        __builtin_amdgcn_s_setprio(0);

        // online softmax (exp2 domain); lane owns q row qin, k = ni*16+quad*4+reg
        const bool diag = (c == qt);
        float tmx[4];
        #pragma unroll
        for (int ni = 0; ni < 4; ++ni) {
            #pragma unroll
            for (int reg = 0; reg < 4; ++reg) {
                float s = sacc[ni][reg];
                if (diag && (ni * 16 + quad * 4 + reg > qin)) s = NEG_BIG;
                sacc[ni][reg] = s;
            }
            tmx[ni] = fmaxf(fmaxf(sacc[ni][0], sacc[ni][1]),
                            fmaxf(sacc[ni][2], sacc[ni][3]));
        }
        float pmax = fmaxf(fmaxf(tmx[0], tmx[1]), fmaxf(tmx[2], tmx[3]));
        pmax = fmaxf(pmax, __shfl_xor(pmax, 16));   // row-uniform across quads
        pmax = fmaxf(pmax, __shfl_xor(pmax, 32));

        // T13 defer-max: only rescale when some row's max grew by > 11 (log2)
        if (!__all((int)(pmax - m <= 11.0f))) {
            const float mx = fmaxf(m, pmax);
            const float alpha = exp2g(m - mx);
            m = mx;
            l *= alpha;
            #pragma unroll
            for (int reg = 0; reg < 4; ++reg) {
                const float ar = __shfl(alpha, quad * 4 + reg);
                #pragma unroll
                for (int nd = 0; nd < 4; ++nd) oacc[nd][reg] *= ar;
            }
        }

        float rs = 0.f;
        bf16x4 pa[4];
        #pragma unroll
        for (int ni = 0; ni < 4; ++ni) {
            const float p0 = exp2g(sacc[ni][0] - m);
            const float p1 = exp2g(sacc[ni][1] - m);
            const float p2 = exp2g(sacc[ni][2] - m);
            const float p3 = exp2g(sacc[ni][3] - m);
            rs += (p0 + p1) + (p2 + p3);
            union { bf16x4 v; u32 d[2]; } pk;
            asm("v_cvt_pk_bf16_f32 %0, %1, %2" : "=v"(pk.d[0]) : "v"(p0), "v"(p1));
            asm("v_cvt_pk_bf16_f32 %0, %1, %2" : "=v"(pk.d[1]) : "v"(p2), "v"(p3));
            pa[ni] = pk.v;
        }
        rs += __shfl_xor(rs, 16);
        rs += __shfl_xor(rs, 32);
        l += rs;

        // PV: oacc[nd](row q = quad*4+reg, col d = nd*16+l16) += P·V
        __builtin_amdgcn_s_setprio(1);
        #pragma unroll
        for (int ks = 0; ks < 4; ++ks) {
            #pragma unroll
            for (int nd = 0; nd < 4; ++nd) {
                const bf16x4 vf = *(const bf16x4*)tptr8c(Vc, nd * 16 + l16, ks * 16 + quad * 4);
                oacc[nd] = __builtin_amdgcn_mfma_f32_16x16x16bf16_1k(pa[ks], vf, oacc[nd], 0, 0, 0);
            }
        }
        __builtin_amdgcn_s_setprio(0);

        // commit prefetched tile into the other buffer; single barrier per tile
        const int nxt = cur ^ 1;
        #pragma unroll
        for (int i = 0; i < 2; ++i) {
            const int cc = i * 256 + t;
            const int row = cc >> 3, col8 = (cc & 7) * 8;
            *(bf16x8*)tptr(&Ks[nxt][0], row, col8) = kpre[i];
            *(bf16x8*)tptr(&Vs[nxt][0], row, col8) = vpre[i];
        }
        __syncthreads();
        cur = nxt;
    }

    // epilogue: row q = quad*4+reg needs l from lane q
    #pragma unroll
    for (int reg = 0; reg < 4; ++reg) {
        const float il = 1.f / __shfl(l, quad * 4 + reg);
        const int q = q0 + wave * 16 + quad * 4 + reg;
        #pragma unroll
        for (int nd = 0; nd < 4; ++nd) {
            const int d = nd * 16 + l16;
            CTXb[(size_t)(b * SEQ + q) * EMB + h * DH + d] = f2b(oacc[nd][reg] * il);
        }
    }
}

// ===========================================================================
// R9-proven kernels (fallback QKV + shared attention + out-proj)
// ===========================================================================

__global__ __launch_bounds__(256) void qkv_proj_mfma(
    const float* __restrict__ Xk, const float* __restrict__ Xv, const float* __restrict__ Xq,
    const float* __restrict__ Wk, const float* __restrict__ Wv, const float* __restrict__ Wq,
    u16* __restrict__ Kw, u16* __restrict__ Vw, u16* __restrict__ Qw)
{
    __shared__ u16 As[128][LDP];
    __shared__ u16 Bs[64][LDP];

    const int which = blockIdx.z;
    const float* __restrict__ X = (which == 0) ? Xk : (which == 1) ? Xv : Xq;
    const float* __restrict__ W = (which == 0) ? Wk : (which == 1) ? Wv : Wq;

    const int h    = blockIdx.y;
    const int m0   = blockIdx.x * 128;
    const int t    = threadIdx.x;
    const int wave = t >> 6, lane = t & 63;
    const int quad = lane >> 4, l16 = lane & 15;

    f32x4 acc[2][4];
    #pragma unroll
    for (int mi = 0; mi < 2; ++mi)
        #pragma unroll
        for (int ni = 0; ni < 4; ++ni) zero4(acc[mi][ni]);

    const size_t wbase = (size_t)h * EMB * DH;
    for (int k0 = 0; k0 < EMB; k0 += 64) {
        #pragma unroll
        for (int i = 0; i < 8; ++i) {
            const int idx = i * 256 + t;
            const int r = idx >> 4, c4 = (idx & 15) * 4;
            const float4 v = *(const float4*)(X + (size_t)(m0 + r) * EMB + k0 + c4);
            *(ushort4*)&As[r][c4] = pk4(v.x, v.y, v.z, v.w);
        }
        #pragma unroll
        for (int i = 0; i < 4; ++i) {
            const int d  = t & 63;
            const int e0 = (t >> 6) * 4 + i * 16;
            const float v0 = W[wbase + (size_t)(k0 + e0 + 0) * DH + d];
            const float v1 = W[wbase + (size_t)(k0 + e0 + 1) * DH + d];
            const float v2 = W[wbase + (size_t)(k0 + e0 + 2) * DH + d];
            const float v3 = W[wbase + (size_t)(k0 + e0 + 3) * DH + d];
            *(ushort4*)&Bs[d][e0] = pk4(v0, v1, v2, v3);
        }
        __syncthreads();

        #pragma unroll
        for (int kb = 0; kb < 2; ++kb) {
            bf16x8 bfr[4];
            #pragma unroll
            for (int ni = 0; ni < 4; ++ni)
                bfr[ni] = *(const bf16x8*)&Bs[ni * 16 + l16][kb * 32 + quad * 8];
            #pragma unroll
            for (int mi = 0; mi < 2; ++mi) {
                const bf16x8 af = *(const bf16x8*)&As[wave * 32 + mi * 16 + l16][kb * 32 + quad * 8];
                #pragma unroll
                for (int ni = 0; ni < 4; ++ni)
                    acc[mi][ni] = __builtin_amdgcn_mfma_f32_16x16x32_bf16(af, bfr[ni], acc[mi][ni], 0, 0, 0);
            }
        }
        __syncthreads();
    }

    const int b  = m0 >> 10;
    const int bh = b * HEADS + h;
    u16* __restrict__ RowDst = (which == 0) ? Kw : Qw;
    #pragma unroll
    for (int mi = 0; mi < 2; ++mi) {
        const int s_base = (m0 & (SEQ - 1)) + wave * 32 + mi * 16 + quad * 4;
        #pragma unroll
        for (int ni = 0; ni < 4; ++ni) {
            const int d = ni * 16 + l16;
            if (which != 1) {
                #pragma unroll
                for (int reg = 0; reg < 4; ++reg)
                    RowDst[((size_t)bh * SEQ + s_base + reg) * DH + d] = f2b(acc[mi][ni][reg]);
            } else {
                *(ushort4*)(Vw + ((size_t)bh * DH + d) * SEQ + s_base) =
                    pk4(acc[mi][ni][0], acc[mi][ni][1], acc[mi][ni][2], acc[mi][ni][3]);
            }
        }
    }
}

template<bool QWS, bool TOWS>
__global__ __launch_bounds__(256) void attn_flash(
    const float* __restrict__ Xq, const float* __restrict__ Wq,
    const u16* __restrict__ Qg, const u16* __restrict__ Kg, const u16* __restrict__ Vg,
    u16* __restrict__ CTXb, float* __restrict__ CTXf)
{
    __shared__ u16 Qs[64][LDP];
    union KVU {
        struct { u16 Ks[64][LDP]; u16 Vt[64][LDP]; } kv;
        struct { u16 Xs[64][LDP]; u16 WT[64][LDP]; } pr;
    };
    __shared__ KVU uu;
    __shared__ u16 Ps[64][LDP];

    const int t    = threadIdx.x;
    const int wave = t >> 6, lane = t & 63;
    const int quad = lane >> 4, l16 = lane & 15;
    const int qt = blockIdx.x, bh = blockIdx.y;
    const int b  = bh >> 4, h = bh & (HEADS - 1);
    const int q0 = qt * 64;

    if (QWS) {
        #pragma unroll
        for (int i = 0; i < 4; ++i) {
            const int idx = i * 256 + t;
            const int r = idx >> 4, c4 = (idx & 15) * 4;
            *(ushort4*)&Qs[r][c4] = *(const ushort4*)(Qg + ((size_t)bh * SEQ + q0 + r) * DH + c4);
        }
    } else {
        f32x4 qacc[4];
        #pragma unroll
        for (int ni = 0; ni < 4; ++ni) zero4(qacc[ni]);
        const size_t wbase = (size_t)h * EMB * DH;
        for (int k0 = 0; k0 < EMB; k0 += 64) {
            #pragma unroll
            for (int i = 0; i < 4; ++i) {
                const int idx = i * 256 + t;
                const int r = idx >> 4, c4 = (idx & 15) * 4;
                const float4 v = *(const float4*)(Xq + (size_t)(b * SEQ + q0 + r) * EMB + k0 + c4);
                *(ushort4*)&uu.pr.Xs[r][c4] = pk4(v.x, v.y, v.z, v.w);
            }
            #pragma unroll
            for (int i = 0; i < 4; ++i) {
                const int d  = t & 63;
                const int e0 = (t >> 6) * 4 + i * 16;
                const float v0 = Wq[wbase + (size_t)(k0 + e0 + 0) * DH + d];
                const float v1 = Wq[wbase + (size_t)(k0 + e0 + 1) * DH + d];
                const float v2 = Wq[wbase + (size_t)(k0 + e0 + 2) * DH + d];
                const float v3 = Wq[wbase + (size_t)(k0 + e0 + 3) * DH + d];
                *(ushort4*)&uu.pr.WT[d][e0] = pk4(v0, v1, v2, v3);
            }
            __syncthreads();
            #pragma unroll
            for (int kb = 0; kb < 2; ++kb) {
                const bf16x8 af = *(const bf16x8*)&uu.pr.Xs[wave * 16 + l16][kb * 32 + quad * 8];
                #pragma unroll
                for (int ni = 0; ni < 4; ++ni) {
                    const bf16x8 bf = *(const bf16x8*)&uu.pr.WT[ni * 16 + l16][kb * 32 + quad * 8];
                    qacc[ni] = __builtin_amdgcn_mfma_f32_16x16x32_bf16(af, bf, qacc[ni], 0, 0, 0);
                }
            }
            __syncthreads();
        }
        #pragma unroll
        for (int ni = 0; ni < 4; ++ni)
            #pragma unroll
            for (int reg = 0; reg < 4; ++reg)
                Qs[wave * 16 + quad * 4 + reg][ni * 16 + l16] = f2b(qacc[ni][reg]);
    }

    float m[4], l[4];
    #pragma unroll
    for (int reg = 0; reg < 4; ++reg) { m[reg] = NEG_BIG; l[reg] = 0.f; }
    f32x4 oacc[4];
    #pragma unroll
    for (int ni = 0; ni < 4; ++ni) zero4(oacc[ni]);
    __syncthreads();

    for (int c = 0; c <= qt; ++c) {
        const int k0 = c * 64;

        #pragma unroll
        for (int i = 0; i < 4; ++i) {
            const int idx = i * 256 + t;
            const int r = idx >> 4, c4 = (idx & 15) * 4;
            *(ushort4*)&uu.kv.Ks[r][c4] = *(const ushort4*)(Kg + ((size_t)bh * SEQ + k0 + r) * DH + c4);
        }
        #pragma unroll
        for (int i = 0; i < 4; ++i) {
            const int idx = i * 256 + t;
            const int r = idx >> 4, c4 = (idx & 15) * 4;
            *(ushort4*)&uu.kv.Vt[r][c4] = *(const ushort4*)(Vg + ((size_t)bh * DH + r) * SEQ + k0 + c4);
        }
        __syncthreads();

        f32x4 sacc[4];
        #pragma unroll
        for (int ni = 0; ni < 4; ++ni) zero4(sacc[ni]);
        #pragma unroll
        for (int kb = 0; kb < 2; ++kb) {
            const bf16x8 af = *(const bf16x8*)&Qs[wave * 16 + l16][kb * 32 + quad * 8];
            #pragma unroll
            for (int ni = 0; ni < 4; ++ni) {
                const bf16x8 bf = *(const bf16x8*)&uu.kv.Ks[ni * 16 + l16][kb * 32 + quad * 8];
                sacc[ni] = __builtin_amdgcn_mfma_f32_16x16x32_bf16(af, bf, sacc[ni], 0, 0, 0);
            }
        }

        const bool diag = (c == qt);
        #pragma unroll
        for (int reg = 0; reg < 4; ++reg) {
            const int rloc = quad * 4 + reg;
            float sv[4];
            #pragma unroll
            for (int ni = 0; ni < 4; ++ni) {
                float s = sacc[ni][reg] * 0.03125f;
                if (diag && (ni * 16 + l16 > wave * 16 + rloc)) s = NEG_BIG;
                sv[ni] = s;
            }
            float mx = fmaxf(fmaxf(sv[0], sv[1]), fmaxf(sv[2], sv[3]));
            mx = fmaxf(mx, m[reg]);
            #pragma unroll
            for (int off = 1; off < 16; off <<= 1) mx = fmaxf(mx, __shfl_xor(mx, off));
            const float alpha = __expf(m[reg] - mx);
            float rs = 0.f;
            #pragma unroll
            for (int ni = 0; ni < 4; ++ni) {
                const float p = __expf(sv[ni] - mx);
                Ps[wave * 16 + rloc][ni * 16 + l16] = f2b(p);
                rs += p;
            }
            #pragma unroll
            for (int off = 1; off < 16; off <<= 1) rs += __shfl_xor(rs, off);
            l[reg] = l[reg] * alpha + rs;
            m[reg] = mx;
            #pragma unroll
            for (int ni = 0; ni < 4; ++ni) oacc[ni][reg] *= alpha;
        }
        __syncthreads();

        #pragma unroll
        for (int kb = 0; kb < 2; ++kb) {
            const bf16x8 af = *(const bf16x8*)&Ps[wave * 16 + l16][kb * 32 + quad * 8];
            #pragma unroll
            for (int ni = 0; ni < 4; ++ni) {
                const bf16x8 bf = *(const bf16x8*)&uu.kv.Vt[ni * 16 + l16][kb * 32 + quad * 8];
                oacc[ni] = __builtin_amdgcn_mfma_f32_16x16x32_bf16(af, bf, oacc[ni], 0, 0, 0);
            }
        }
        __syncthreads();
    }

    float il[4];
    #pragma unroll
    for (int reg = 0; reg < 4; ++reg) il[reg] = 1.f / l[reg];
    #pragma unroll
    for (int ni = 0; ni < 4; ++ni) {
        const int d = ni * 16 + l16;
        #pragma unroll
        for (int reg = 0; reg < 4; ++reg) {
            const int q = wave * 16 + quad * 4 + reg;
            const float val = oacc[ni][reg] * il[reg];
            const size_t off = ((size_t)(b * SEQ + q0 + q)) * EMB + h * DH + d;
            if (TOWS) CTXb[off] = f2b(val);
            else      CTXf[off] = val;
        }
    }
}

__global__ __launch_bounds__(256) void out_proj_mfma(
    const u16* __restrict__ CTXb, const float* __restrict__ Wo,
    const float* __restrict__ bo, float* __restrict__ OUT)
{
    __shared__ u16 As[128][LDP];
    __shared__ u16 Bs[64][LDP];

    const int m0 = blockIdx.x * 128;
    const int n0 = blockIdx.y * 64;
    const int t = threadIdx.x;
    const int wave = t >> 6, lane = t & 63;
    const int quad = lane >> 4, l16 = lane & 15;

    f32x4 acc[2][4];
    #pragma unroll
    for (int mi = 0; mi < 2; ++mi)
        #pragma unroll
        for (int ni = 0; ni < 4; ++ni) zero4(acc[mi][ni]);

    for (int k0 = 0; k0 < EMB; k0 += 64) {
        #pragma unroll
        for (int i = 0; i < 8; ++i) {
            const int idx = i * 256 + t;
            const int r = idx >> 4, c4 = (idx & 15) * 4;
            *(ushort4*)&As[r][c4] = *(const ushort4*)(CTXb + (size_t)(m0 + r) * EMB + k0 + c4);
        }
        #pragma unroll
        for (int i = 0; i < 4; ++i) {
            const int d  = t & 63;
            const int e0 = (t >> 6) * 4 + i * 16;
            const float v0 = Wo[(size_t)(k0 + e0 + 0) * EMB + n0 + d];
            const float v1 = Wo[(size_t)(k0 + e0 + 1) * EMB + n0 + d];
            const float v2 = Wo[(size_t)(k0 + e0 + 2) * EMB + n0 + d];
            const float v3 = Wo[(size_t)(k0 + e0 + 3) * EMB + n0 + d];
            *(ushort4*)&Bs[d][e0] = pk4(v0, v1, v2, v3);
        }
        __syncthreads();
        #pragma unroll
        for (int kb = 0; kb < 2; ++kb) {
            bf16x8 bfr[4];
            #pragma unroll
            for (int ni = 0; ni < 4; ++ni)
                bfr[ni] = *(const bf16x8*)&Bs[ni * 16 + l16][kb * 32 + quad * 8];
            #pragma unroll
            for (int mi = 0; mi < 2; ++mi) {
                const bf16x8 af = *(const bf16x8*)&As[wave * 32 + mi * 16 + l16][kb * 32 + quad * 8];
                #pragma unroll
                for (int ni = 0; ni < 4; ++ni)
                    acc[mi][ni] = __builtin_amdgcn_mfma_f32_16x16x32_bf16(af, bfr[ni], acc[mi][ni], 0, 0, 0);
            }
        }
        __syncthreads();
    }

    #pragma unroll
    for (int mi = 0; mi < 2; ++mi) {
        const int row = m0 + wave * 32 + mi * 16 + quad * 4;
        #pragma unroll
        for (int ni = 0; ni < 4; ++ni) {
            const int col = n0 + ni * 16 + l16;
            const float bias = bo[col];
            #pragma unroll
            for (int reg = 0; reg < 4; ++reg) {
                float v = acc[mi][ni][reg] + bias;
                if (v < 0.f) v = 0.f;
                OUT[(size_t)(row + reg) * EMB + col] = v;
            }
        }
    }
}

__global__ __launch_bounds__(256) void out_proj_inplace(
    float* __restrict__ OUT, const float* __restrict__ Wo, const float* __restrict__ bo)
{
    __shared__ float Xs[8][EMB];
    const int t    = threadIdx.x;
    const int row0 = blockIdx.x * 8;
    {
        const float4* src = (const float4*)(OUT + (size_t)row0 * EMB);
        float4* dst = (float4*)&Xs[0][0];
        #pragma unroll
        for (int i = 0; i < 8; ++i) dst[i * 256 + t] = src[i * 256 + t];
    }
    __syncthreads();
    const int r  = t >> 5;
    const int j0 = (t & 31) * 2;
    const float* xrow = Xs[r];
    for (int jb = 0; jb < 16; ++jb) {
        const int j = jb * 64 + j0;
        float a0, a1;
        dot2_f32(xrow, Wo + j, EMB, a0, a1);
        a0 += bo[j];     if (a0 < 0.f) a0 = 0.f;
        a1 += bo[j + 1]; if (a1 < 0.f) a1 = 0.f;
        float* op = OUT + (size_t)(row0 + r) * EMB + j;
        op[0] = a0; op[1] = a1;
    }
}

// ---------------------------------------------------------------------------
extern "C" void kernel_launch(void* const* d_in, const int* in_sizes, int n_in,
                              void* d_out, int out_size, void* d_ws, size_t ws_size,
                              hipStream_t stream)
{
    const float* Xk = (const float*)d_in[0];
    const float* Xv = (const float*)d_in[1];
    const float* Xq = (const float*)d_in[2];
    const float* Wk = (const float*)d_in[3];
    const float* Wv = (const float*)d_in[4];
    const float* Wq = (const float*)d_in[5];
    const float* Wo = (const float*)d_in[6];
    const float* bo = (const float*)d_in[7];
    float* OUT = (float*)d_out;
    (void)in_sizes; (void)n_in; (void)out_size;

    const size_t SEGE = (size_t)BH * SEQ * DH;        // 4,194,304 elems
    const size_t SEGB = SEGE * sizeof(u16);           // 8 MB

    // Tier A ws layout (u16 elems):
    //   XB (3*4M, aliased by CTX after gemm_qkv) | WT (3*1M) | WoT (1M) | Qw | Kw | Vt
    const size_t XB_OFF  = 0;
    const size_t WT_OFF  = 3 * SEGE;                  // 12,582,912
    const size_t WOT_OFF = WT_OFF + 3 * (EMB * EMB / 64) * 64;  // +3*1,048,576
    const size_t QW_OFF  = WOT_OFF + (size_t)EMB * EMB;
    const size_t KW_OFF  = QW_OFF + SEGE;
    const size_t VT_OFF  = KW_OFF + SEGE;
    const size_t TIER_A_BYTES = (VT_OFF + SEGE) * sizeof(u16);  // 58,720,256

    if (ws_size >= TIER_A_BYTES) {
        u16* W16 = (u16*)d_ws;
        u16* XB  = W16 + XB_OFF;
        u16* WT  = W16 + WT_OFF;
        u16* WoT = W16 + WOT_OFF;
        u16* Qw  = W16 + QW_OFF;
        u16* Kw  = W16 + KW_OFF;
        u16* Vt  = W16 + VT_OFF;
        u16* CTX = XB;                                // alias (XB dead after gemm_qkv)

        convert_x<<<dim3(4096, 3), 256, 0, stream>>>(Xk, Xv, Xq, XB);
        transpose_w<<<dim3(256, 4), 256, 0, stream>>>(Wk, Wv, Wq, Wo, WT, WoT);
        gemm128<0><<<dim3(32, 8, 3), 256, 0, stream>>>(XB, WT, Qw, Kw, Vt, nullptr, nullptr);
        attn_flash2<<<dim3(SEQ / 64, BH), 256, 0, stream>>>(Qw, Kw, Vt, CTX);
        gemm128<1><<<dim3(32, 8, 1), 256, 0, stream>>>(CTX, WoT, nullptr, nullptr, nullptr, bo, OUT);
    } else if (ws_size >= 4 * SEGB) {
        u16* Qw = (u16*)d_ws;
        u16* Kw = Qw + SEGE;
        u16* Vw = Kw + SEGE;
        u16* CT = Vw + SEGE;
        qkv_proj_mfma<<<dim3(32, HEADS, 3), 256, 0, stream>>>(Xk, Xv, Xq, Wk, Wv, Wq, Kw, Vw, Qw);
        attn_flash<true, true><<<dim3(SEQ / 64, BH), 256, 0, stream>>>(
            Xq, Wq, Qw, Kw, Vw, CT, nullptr);
        out_proj_mfma<<<dim3(32, EMB / 64), 256, 0, stream>>>(CT, Wo, bo, OUT);
    } else if (ws_size >= 3 * SEGB) {
        u16* Kw = (u16*)d_ws;
        u16* Vw = Kw + SEGE;
        u16* CT = Vw + SEGE;
        qkv_proj_mfma<<<dim3(32, HEADS, 2), 256, 0, stream>>>(Xk, Xv, Xq, Wk, Wv, Wq, Kw, Vw, nullptr);
        attn_flash<false, true><<<dim3(SEQ / 64, BH), 256, 0, stream>>>(
            Xq, Wq, nullptr, Kw, Vw, CT, nullptr);
        out_proj_mfma<<<dim3(32, EMB / 64), 256, 0, stream>>>(CT, Wo, bo, OUT);
    } else {
        u16* Kw = (u16*)d_ws;
        u16* Vw = Kw + SEGE;
        qkv_proj_mfma<<<dim3(32, HEADS, 2), 256, 0, stream>>>(Xk, Xv, Xq, Wk, Wv, Wq, Kw, Vw, nullptr);
        attn_flash<false, false><<<dim3(SEQ / 64, BH), 256, 0, stream>>>(
            Xq, Wq, nullptr, Kw, Vw, nullptr, OUT);
        out_proj_inplace<<<dim3(BS / 8), 256, 0, stream>>>(OUT, Wo, bo);
    }
}